// Round 20
// baseline (168.564 us; speedup 1.0000x reference)
//
#include <hip/hip_runtime.h>
#include <stdint.h>
#include <math.h>

#define B_SZ 4
#define S_LEN 2048
#define NH 16
#define HD 64
#define DM 1024
#define M_ROWS (B_SZ * S_LEN)  // 8192
#define NQ 16                  // q-tiles of 128

typedef __bf16 bf16x8 __attribute__((ext_vector_type(8)));
typedef __bf16 bf16x4 __attribute__((ext_vector_type(4)));
typedef float f32x4 __attribute__((ext_vector_type(4)));
typedef unsigned int u32x2 __attribute__((ext_vector_type(2)));

typedef __attribute__((address_space(3))) void lds_t;
typedef __attribute__((address_space(1))) const void gbl_t;

__device__ __forceinline__ unsigned cvtpk_bf16(float a, float b) {
  unsigned r;
  asm("v_cvt_pk_bf16_f32 %0, %1, %2" : "=v"(r) : "v"(a), "v"(b));
  return r;
}

// hardware exp2 (v_exp_f32 IS 2^x)
__device__ __forceinline__ float exp2_hw(float x) {
  float r;
  asm("v_exp_f32 %0, %1" : "=v"(r) : "v"(x));
  return r;
}

// ---------------- fp32 -> bf16 convert (x + all 4 weights, one launch) -------
__global__ void cvt_all(const float* __restrict__ x,
                        const float* __restrict__ wq, const float* __restrict__ wk,
                        const float* __restrict__ wv, const float* __restrict__ wo,
                        __bf16* __restrict__ xb, __bf16* __restrict__ wdst) {
  const int NX4 = M_ROWS * DM / 4;
  const int NW4 = DM * DM / 4;
  const int TOT = NX4 + 4 * NW4;
  int i = blockIdx.x * blockDim.x + threadIdx.x;
  int stride = gridDim.x * blockDim.x;
  for (; i < TOT; i += stride) {
    const float* src;
    __bf16* dst;
    int idx;
    if (i < NX4) {
      src = x; dst = xb; idx = i;
    } else {
      int j = i - NX4;
      int sel = j >> 18;
      src = (sel == 0) ? wq : (sel == 1) ? wk : (sel == 2) ? wv : wo;
      dst = wdst + (size_t)sel * DM * DM;
      idx = j & (NW4 - 1);
    }
    f32x4 v = reinterpret_cast<const f32x4*>(src)[idx];
    bf16x4 o;
    o[0] = (__bf16)v[0]; o[1] = (__bf16)v[1];
    o[2] = (__bf16)v[2]; o[3] = (__bf16)v[3];
    reinterpret_cast<bf16x4*>(dst)[idx] = o;
  }
}

// ---------------- GEMM, 128x128, BK=64, swizzled LDS ------------------------
// XCD-chunked + 8x8 supertiles: per-generation footprint W 2MB + A 2MB ~ L2.
// MODE 0: QKV epilogue (N=3072): Q*(0.125*log2e) / K / V^T ; MODE 1: fp32 out
template <int MODE>
__global__ __launch_bounds__(256, 2) void gemm64(
    const unsigned short* __restrict__ A, const unsigned short* __restrict__ BT,
    __bf16* __restrict__ Qb, __bf16* __restrict__ Kb, __bf16* __restrict__ Vt,
    float* __restrict__ Out, int NX) {
  __shared__ __align__(16) unsigned short As[128 * 64];
  __shared__ __align__(16) unsigned short Bs[128 * 64];

  const int t = threadIdx.x, lane = t & 63, w = t >> 6;
  const int wm = w >> 1, wn = w & 1;
  const int g = lane >> 4, c = lane & 15;

  const int nwg = (int)gridDim.x;
  const int cpx = nwg >> 3;
  const int bid = (int)blockIdx.x;
  const int xcd = bid & 7;
  const int u = bid >> 3;
  const int R = cpx / NX;
  const int st = u / (8 * R);
  const int v = u % (8 * R);
  const int bx = st * 8 + (v & 7);
  const int by = xcd * R + (v >> 3);
  const int tm0 = by * 128, tn0 = bx * 128;
  const int K = DM;

  const int srow = t >> 3;
  const int scolb = (t & 7) << 4;
  const int ssw = scolb ^ ((srow & 7) << 4);
  const uint8_t* gA0 = (const uint8_t*)A + ((size_t)(tm0 + srow) * K) * 2 + ssw;
  const uint8_t* gB0 = (const uint8_t*)BT + ((size_t)(tn0 + srow) * K) * 2 + ssw;
  uint8_t* lA0 = (uint8_t*)As + t * 16;
  uint8_t* lB0 = (uint8_t*)Bs + t * 16;
  const int kxor = (c & 7) << 4;

  f32x4 acc[4][4] = {};

  for (int k0 = 0; k0 < K; k0 += 64) {
#pragma unroll
    for (int q = 0; q < 4; ++q) {
      __builtin_amdgcn_global_load_lds((gbl_t*)(gA0 + ((size_t)q * 32 * K + k0) * 2),
                                       (lds_t*)(lA0 + q * 4096), 16, 0, 0);
      __builtin_amdgcn_global_load_lds((gbl_t*)(gB0 + ((size_t)q * 32 * K + k0) * 2),
                                       (lds_t*)(lB0 + q * 4096), 16, 0, 0);
    }
    __syncthreads();

#pragma unroll
    for (int ks = 0; ks < 2; ++ks) {
      bf16x8 af[4], bfm[4];
#pragma unroll
      for (int mb = 0; mb < 4; ++mb)
        af[mb] = *reinterpret_cast<const bf16x8*>(
            (const uint8_t*)As + (wm * 64 + mb * 16 + c) * 128 + ((ks * 64 + g * 16) ^ kxor));
#pragma unroll
      for (int nb = 0; nb < 4; ++nb)
        bfm[nb] = *reinterpret_cast<const bf16x8*>(
            (const uint8_t*)Bs + (wn * 64 + nb * 16 + c) * 128 + ((ks * 64 + g * 16) ^ kxor));
      __builtin_amdgcn_s_setprio(1);
#pragma unroll
      for (int mb = 0; mb < 4; ++mb)
#pragma unroll
        for (int nb = 0; nb < 4; ++nb)
          acc[mb][nb] = __builtin_amdgcn_mfma_f32_16x16x32_bf16(af[mb], bfm[nb], acc[mb][nb], 0, 0, 0);
      __builtin_amdgcn_s_setprio(0);
    }
    __syncthreads();
  }

  const int rm0 = tm0 + wm * 64;
  const int cn0 = tn0 + wn * 64;
  const int sel = tn0 >> 10;
#pragma unroll
  for (int mb = 0; mb < 4; ++mb) {
#pragma unroll
    for (int nb = 0; nb < 4; ++nb) {
      f32x4 v2 = acc[mb][nb];
#pragma unroll
      for (int j = 0; j < 4; ++j) {
        int rm = rm0 + mb * 16 + g * 4 + j;
        int cn = cn0 + nb * 16 + c;
        float val = v2[j];
        if (MODE == 0) {
          int b = rm >> 11, s = rm & 2047;
          int dmn = cn & 1023;
          int h = dmn >> 6, d = dmn & 63;
          if (sel == 0) {
            Qb[(((size_t)(b * NH + h) * S_LEN + s) << 6) + d] = (__bf16)(val * 0.18033688f);
          } else if (sel == 1) {
            Kb[(((size_t)(b * NH + h) * S_LEN + s) << 6) + d] = (__bf16)val;
          } else {
            Vt[((size_t)(b * NH + h) * HD + d) * S_LEN + s] = (__bf16)val;
          }
        } else {
          Out[(size_t)rm * DM + cn] = val;
        }
      }
    }
  }
}

// ---------------- flash attention (causal, no-max exp2 softmax) --------------
// 1D grid, XCD-chunked work remap (T1). SPLIT=1: no partials, no combine;
// heavy-first q-tile ordering balances; Aout written directly.
template <int SPLIT>
__global__ __launch_bounds__(256, 3) void attn_kernel(
    const unsigned short* __restrict__ Qb, const unsigned short* __restrict__ Kb,
    const unsigned short* __restrict__ Vt, __bf16* __restrict__ Aout,
    __bf16* __restrict__ AP, float* __restrict__ Lp) {
  __shared__ __align__(16) unsigned short KVs[2][8192];   // 32KB
  __shared__ __align__(16) unsigned short Ps[4][32 * 72]; // per-wave P, 18KB

  const int t = threadIdx.x, lane = t & 63, w = t >> 6;
  const int g = lane >> 4, c = lane & 15;

  const int lin = (int)blockIdx.x;
  const int work = (lin & 7) * ((int)gridDim.x >> 3) + (lin >> 3);
  const int sp = work % SPLIT;
  const int qx = (NQ - 1) - ((work / SPLIT) & (NQ - 1));  // heavy q-tiles first
  const int bh = work / (SPLIT * NQ);
  const int b = bh >> 4, h = bh & 15;
  const int q0 = qx * 128 + w * 32;

  const unsigned short* Qp = Qb + (size_t)bh * S_LEN * HD;
  const uint8_t* Kg8 = (const uint8_t*)(Kb + (size_t)bh * S_LEN * HD);
  const uint8_t* Vg8 = (const uint8_t*)(Vt + (size_t)bh * HD * S_LEN);

  const int sr = t >> 3;
  const int scb = ((t & 7) << 4) ^ ((sr & 7) << 4);
  const uint8_t* Kst = Kg8 + (size_t)sr * 128 + scb;
  const uint8_t* Vst = Vg8 + (size_t)sr * (S_LEN * 2) + scb;
  uint8_t* Ls = (uint8_t*)&KVs[0][0];

#define STAGE(buf, kvb_) do {                                                  \
    uint8_t* kd = Ls + (buf) * 16384 + t * 16;                                 \
    const uint8_t* kg = Kst + (size_t)(kvb_) * 128;                            \
    const uint8_t* vg = Vst + (size_t)(kvb_) * 2;                              \
    __builtin_amdgcn_global_load_lds((gbl_t*)kg, (lds_t*)kd, 16, 0, 0);        \
    __builtin_amdgcn_global_load_lds((gbl_t*)(kg + 32 * 128),                  \
                                     (lds_t*)(kd + 4096), 16, 0, 0);           \
    __builtin_amdgcn_global_load_lds((gbl_t*)vg, (lds_t*)(kd + 8192), 16, 0, 0);\
    __builtin_amdgcn_global_load_lds((gbl_t*)(vg + (size_t)32 * S_LEN * 2),    \
                                     (lds_t*)(kd + 12288), 16, 0, 0);          \
  } while (0)

  bf16x8 qf[2][2];
#pragma unroll
  for (int mb = 0; mb < 2; ++mb)
#pragma unroll
    for (int ks = 0; ks < 2; ++ks)
      qf[mb][ks] = *reinterpret_cast<const bf16x8*>(
          Qp + (size_t)(q0 + mb * 16 + c) * HD + ks * 32 + g * 8);

  bf16x8 onesf;
#pragma unroll
  for (int i = 0; i < 8; ++i) onesf[i] = (__bf16)1.0f;

  f32x4 oacc[2][4] = {};
  f32x4 lacc[2] = {};

  const int kxor = (c & 7) << 4;
  const int n_total = 2 * qx + 2;
  const int chunk = (n_total + SPLIT - 1) / SPLIT;
  int t0 = sp * chunk; if (t0 > n_total) t0 = n_total;
  int t1 = t0 + chunk; if (t1 > n_total) t1 = n_total;
  const int nblk_w = (q0 >> 6) + 1;

  const int st0 = (t0 < n_total) ? t0 : (n_total - 1);
  STAGE(0, st0 * 64);
  __syncthreads();

  __bf16* psw = (__bf16*)&Ps[w][0];
  const int qr = q0 + c;

  for (int kb = t0; kb < t1; ++kb) {
    const int cur = (kb - t0) & 1;
    if (kb + 1 < t1) STAGE(cur ^ 1, (kb + 1) * 64);

    if (kb < nblk_w) {
      const int kvb = kb * 64;
      const uint8_t* KL = Ls + cur * 16384;
      const uint8_t* VL = KL + 8192;

      f32x4 sacc[2][4] = {};
      __builtin_amdgcn_s_setprio(1);
#pragma unroll
      for (int ks = 0; ks < 2; ++ks) {
#pragma unroll
        for (int nb = 0; nb < 4; ++nb) {
          bf16x8 kf = *reinterpret_cast<const bf16x8*>(
              KL + (nb * 16 + c) * 128 + ((ks * 64 + g * 16) ^ kxor));
          sacc[0][nb] = __builtin_amdgcn_mfma_f32_16x16x32_bf16(kf, qf[0][ks], sacc[0][nb], 0, 0, 0);
          sacc[1][nb] = __builtin_amdgcn_mfma_f32_16x16x32_bf16(kf, qf[1][ks], sacc[1][nb], 0, 0, 0);
        }
      }
      __builtin_amdgcn_s_setprio(0);

      bf16x8 vf0[4], vf1[4];
#pragma unroll
      for (int db = 0; db < 4; ++db) {
        vf0[db] = *reinterpret_cast<const bf16x8*>(
            VL + (db * 16 + c) * 128 + ((g * 16) ^ kxor));
        vf1[db] = *reinterpret_cast<const bf16x8*>(
            VL + (db * 16 + c) * 128 + ((64 + g * 16) ^ kxor));
      }

      if (kb == nblk_w - 1) {
#pragma unroll
        for (int mb = 0; mb < 2; ++mb) {
          const int qrm = qr + mb * 16;
#pragma unroll
          for (int nb = 0; nb < 4; ++nb) {
            const int key0 = kvb + nb * 16 + g * 4;
            float p0 = (key0 + 0 <= qrm) ? exp2_hw(sacc[mb][nb][0]) : 0.f;
            float p1 = (key0 + 1 <= qrm) ? exp2_hw(sacc[mb][nb][1]) : 0.f;
            float p2 = (key0 + 2 <= qrm) ? exp2_hw(sacc[mb][nb][2]) : 0.f;
            float p3 = (key0 + 3 <= qrm) ? exp2_hw(sacc[mb][nb][3]) : 0.f;
            u32x2 pk = {cvtpk_bf16(p0, p1), cvtpk_bf16(p2, p3)};
            *reinterpret_cast<u32x2*>(psw + (mb * 16 + c) * 72 + nb * 16 + g * 4) = pk;
          }
        }
      } else {
#pragma unroll
        for (int mb = 0; mb < 2; ++mb)
#pragma unroll
          for (int nb = 0; nb < 4; ++nb) {
            float p0 = exp2_hw(sacc[mb][nb][0]);
            float p1 = exp2_hw(sacc[mb][nb][1]);
            float p2 = exp2_hw(sacc[mb][nb][2]);
            float p3 = exp2_hw(sacc[mb][nb][3]);
            u32x2 pk = {cvtpk_bf16(p0, p1), cvtpk_bf16(p2, p3)};
            *reinterpret_cast<u32x2*>(psw + (mb * 16 + c) * 72 + nb * 16 + g * 4) = pk;
          }
      }

      bf16x8 pf0_0 = *reinterpret_cast<const bf16x8*>(psw + (c) * 72 + g * 8);
      bf16x8 pf0_1 = *reinterpret_cast<const bf16x8*>(psw + (c) * 72 + 32 + g * 8);
      bf16x8 pf1_0 = *reinterpret_cast<const bf16x8*>(psw + (16 + c) * 72 + g * 8);
      bf16x8 pf1_1 = *reinterpret_cast<const bf16x8*>(psw + (16 + c) * 72 + 32 + g * 8);

      __builtin_amdgcn_s_setprio(1);
      lacc[0] = __builtin_amdgcn_mfma_f32_16x16x32_bf16(pf0_0, onesf, lacc[0], 0, 0, 0);
      lacc[0] = __builtin_amdgcn_mfma_f32_16x16x32_bf16(pf0_1, onesf, lacc[0], 0, 0, 0);
      lacc[1] = __builtin_amdgcn_mfma_f32_16x16x32_bf16(pf1_0, onesf, lacc[1], 0, 0, 0);
      lacc[1] = __builtin_amdgcn_mfma_f32_16x16x32_bf16(pf1_1, onesf, lacc[1], 0, 0, 0);

#pragma unroll
      for (int db = 0; db < 4; ++db) {
        oacc[0][db] = __builtin_amdgcn_mfma_f32_16x16x32_bf16(pf0_0, vf0[db], oacc[0][db], 0, 0, 0);
        oacc[0][db] = __builtin_amdgcn_mfma_f32_16x16x32_bf16(pf0_1, vf1[db], oacc[0][db], 0, 0, 0);
        oacc[1][db] = __builtin_amdgcn_mfma_f32_16x16x32_bf16(pf1_0, vf0[db], oacc[1][db], 0, 0, 0);
        oacc[1][db] = __builtin_amdgcn_mfma_f32_16x16x32_bf16(pf1_1, vf1[db], oacc[1][db], 0, 0, 0);
      }
      __builtin_amdgcn_s_setprio(0);
    }
    __syncthreads();
  }
#undef STAGE

  if (SPLIT == 1) {
    float rl[2][4];
#pragma unroll
    for (int mb = 0; mb < 2; ++mb)
#pragma unroll
      for (int j = 0; j < 4; ++j) rl[mb][j] = 1.0f / lacc[mb][j];
#pragma unroll
    for (int mb = 0; mb < 2; ++mb)
#pragma unroll
      for (int db = 0; db < 4; ++db)
#pragma unroll
        for (int j = 0; j < 4; ++j) {
          float o = oacc[mb][db][j] * rl[mb][j];
          int s = q0 + mb * 16 + g * 4 + j;
          int d = db * 16 + c;
          Aout[(size_t)(b * S_LEN + s) * DM + h * HD + d] = (__bf16)o;
        }
  } else if (t0 < nblk_w) {
    __bf16* APs = AP + (size_t)(sp * (B_SZ * NH) + bh) * S_LEN * HD;
    float* Lps = Lp + (size_t)(sp * (B_SZ * NH) + bh) * S_LEN;
#pragma unroll
    for (int mb = 0; mb < 2; ++mb) {
#pragma unroll
      for (int db = 0; db < 4; ++db)
#pragma unroll
        for (int j = 0; j < 4; ++j) {
          int q = q0 + mb * 16 + g * 4 + j;
          APs[(size_t)q * HD + db * 16 + c] = (__bf16)oacc[mb][db][j];
        }
      if (c == 0) {
#pragma unroll
        for (int j = 0; j < 4; ++j)
          Lps[q0 + mb * 16 + g * 4 + j] = lacc[mb][j];
      }
    }
  }
}

// combine (SPLIT=2 fallback): Aout = (Σ live AP)/(Σ live L)
__global__ void attn_combine2(const __bf16* __restrict__ AP, const float* __restrict__ Lp,
                              __bf16* __restrict__ Aout) {
  const int NIT = B_SZ * NH * S_LEN * (HD / 8);
  int i = blockIdx.x * blockDim.x + threadIdx.x;
  int stride = gridDim.x * blockDim.x;
  const size_t SOFF = (size_t)(B_SZ * NH) * S_LEN * HD;
  const size_t LOFF = (size_t)(B_SZ * NH) * S_LEN;
  for (; i < NIT; i += stride) {
    int d8 = i & 7;
    int q = (i >> 3) & (S_LEN - 1);
    int bh = i >> 14;
    size_t base = ((size_t)bh * S_LEN + q) * HD + d8 * 8;
    size_t lbase = (size_t)bh * S_LEN + q;

    const int qx = q >> 7;
    const int chunk = qx + 1;
    const int nblk_w = (q >> 6) + 1;

    float acc8[8];
    {
      bf16x8 a0 = *reinterpret_cast<const bf16x8*>(AP + base);
#pragma unroll
      for (int k = 0; k < 8; ++k) acc8[k] = (float)a0[k];
    }
    float l = Lp[lbase];
    if (chunk < nblk_w) {
      bf16x8 a = *reinterpret_cast<const bf16x8*>(AP + SOFF + base);
#pragma unroll
      for (int k = 0; k < 8; ++k) acc8[k] += (float)a[k];
      l += Lp[LOFF + lbase];
    }
    float rl = 1.0f / l;
    int b = bh >> 4, h = bh & 15;
    bf16x8 o;
#pragma unroll
    for (int k = 0; k < 8; ++k) o[k] = (__bf16)(acc8[k] * rl);
    *reinterpret_cast<bf16x8*>(Aout + ((size_t)(b * S_LEN + q)) * DM + h * HD + d8 * 8) = o;
  }
}

// ---------------- launcher ----------------
extern "C" void kernel_launch(void* const* d_in, const int* in_sizes, int n_in,
                              void* d_out, int out_size, void* d_ws, size_t ws_size,
                              hipStream_t stream) {
  const float* x = (const float*)d_in[0];
  const float* wq = (const float*)d_in[1];
  const float* wk = (const float*)d_in[2];
  const float* wv = (const float*)d_in[3];
  const float* wo = (const float*)d_in[4];
  float* out = (float*)d_out;

  uint8_t* ws = (uint8_t*)d_ws;
  const size_t MB = 1024 * 1024;
  unsigned short* xb   = (unsigned short*)(ws);             // 16 MB (reused as Aout)
  unsigned short* wcat = (unsigned short*)(ws + 16 * MB);   // 6 MB
  unsigned short* wob  = (unsigned short*)(ws + 22 * MB);   // 2 MB
  unsigned short* Qb   = (unsigned short*)(ws + 24 * MB);   // 16 MB
  unsigned short* Kb   = (unsigned short*)(ws + 40 * MB);   // 16 MB
  unsigned short* Vt   = (unsigned short*)(ws + 56 * MB);   // 16 MB

  cvt_all<<<2048, 256, 0, stream>>>(x, wq, wk, wv, wo, (__bf16*)xb, (__bf16*)wcat);

  gemm64<0><<<dim3((3 * DM / 128) * (M_ROWS / 128)), 256, 0, stream>>>(
      xb, wcat, (__bf16*)Qb, (__bf16*)Kb, (__bf16*)Vt, nullptr, 3 * DM / 128);

  __bf16* Aout = (__bf16*)xb;  // x no longer needed
  // SPLIT=1: no partials, no combine; XCD remap + heavy-first balances.
  attn_kernel<1><<<dim3(NQ * B_SZ * NH), 256, 0, stream>>>(
      Qb, Kb, Vt, Aout, nullptr, nullptr);

  gemm64<1><<<dim3((DM / 128) * (M_ROWS / 128)), 256, 0, stream>>>(
      xb, wob, nullptr, nullptr, nullptr, out, DM / 128);
}

// Round 21
// 167.458 us; speedup vs baseline: 1.0066x; 1.0066x over previous
//
#include <hip/hip_runtime.h>
#include <stdint.h>
#include <math.h>

#define B_SZ 4
#define S_LEN 2048
#define NH 16
#define HD 64
#define DM 1024
#define M_ROWS (B_SZ * S_LEN)  // 8192
#define NQ 16                  // q-tiles of 128

typedef __bf16 bf16x8 __attribute__((ext_vector_type(8)));
typedef __bf16 bf16x4 __attribute__((ext_vector_type(4)));
typedef float f32x4 __attribute__((ext_vector_type(4)));
typedef unsigned int u32x2 __attribute__((ext_vector_type(2)));

typedef __attribute__((address_space(3))) void lds_t;
typedef __attribute__((address_space(1))) const void gbl_t;

__device__ __forceinline__ unsigned cvtpk_bf16(float a, float b) {
  unsigned r;
  asm("v_cvt_pk_bf16_f32 %0, %1, %2" : "=v"(r) : "v"(a), "v"(b));
  return r;
}

// hardware exp2 (v_exp_f32 IS 2^x)
__device__ __forceinline__ float exp2_hw(float x) {
  float r;
  asm("v_exp_f32 %0, %1" : "=v"(r) : "v"(x));
  return r;
}

// ---------------- fp32 -> bf16 convert (x + all 4 weights, one launch) -------
__global__ void cvt_all(const float* __restrict__ x,
                        const float* __restrict__ wq, const float* __restrict__ wk,
                        const float* __restrict__ wv, const float* __restrict__ wo,
                        __bf16* __restrict__ xb, __bf16* __restrict__ wdst) {
  const int NX4 = M_ROWS * DM / 4;
  const int NW4 = DM * DM / 4;
  const int TOT = NX4 + 4 * NW4;
  int i = blockIdx.x * blockDim.x + threadIdx.x;
  int stride = gridDim.x * blockDim.x;
  for (; i < TOT; i += stride) {
    const float* src;
    __bf16* dst;
    int idx;
    if (i < NX4) {
      src = x; dst = xb; idx = i;
    } else {
      int j = i - NX4;
      int sel = j >> 18;
      src = (sel == 0) ? wq : (sel == 1) ? wk : (sel == 2) ? wv : wo;
      dst = wdst + (size_t)sel * DM * DM;
      idx = j & (NW4 - 1);
    }
    f32x4 v = reinterpret_cast<const f32x4*>(src)[idx];
    bf16x4 o;
    o[0] = (__bf16)v[0]; o[1] = (__bf16)v[1];
    o[2] = (__bf16)v[2]; o[3] = (__bf16)v[3];
    reinterpret_cast<bf16x4*>(dst)[idx] = o;
  }
}

// ---------------- GEMM, 128x128, BK=64, swizzled LDS ------------------------
// XCD-chunked + 8x8 supertiles: per-generation footprint W 2MB + A 2MB ~ L2.
// MODE 0: QKV epilogue (N=3072): Q*(0.125*log2e) / K / V^T ; MODE 1: fp32 out
template <int MODE>
__global__ __launch_bounds__(256, 2) void gemm64(
    const unsigned short* __restrict__ A, const unsigned short* __restrict__ BT,
    __bf16* __restrict__ Qb, __bf16* __restrict__ Kb, __bf16* __restrict__ Vt,
    float* __restrict__ Out, int NX) {
  __shared__ __align__(16) unsigned short As[128 * 64];
  __shared__ __align__(16) unsigned short Bs[128 * 64];

  const int t = threadIdx.x, lane = t & 63, w = t >> 6;
  const int wm = w >> 1, wn = w & 1;
  const int g = lane >> 4, c = lane & 15;

  const int nwg = (int)gridDim.x;
  const int cpx = nwg >> 3;
  const int bid = (int)blockIdx.x;
  const int xcd = bid & 7;
  const int u = bid >> 3;
  const int R = cpx / NX;
  const int st = u / (8 * R);
  const int v = u % (8 * R);
  const int bx = st * 8 + (v & 7);
  const int by = xcd * R + (v >> 3);
  const int tm0 = by * 128, tn0 = bx * 128;
  const int K = DM;

  const int srow = t >> 3;
  const int scolb = (t & 7) << 4;
  const int ssw = scolb ^ ((srow & 7) << 4);
  const uint8_t* gA0 = (const uint8_t*)A + ((size_t)(tm0 + srow) * K) * 2 + ssw;
  const uint8_t* gB0 = (const uint8_t*)BT + ((size_t)(tn0 + srow) * K) * 2 + ssw;
  uint8_t* lA0 = (uint8_t*)As + t * 16;
  uint8_t* lB0 = (uint8_t*)Bs + t * 16;
  const int kxor = (c & 7) << 4;

  f32x4 acc[4][4] = {};

  for (int k0 = 0; k0 < K; k0 += 64) {
#pragma unroll
    for (int q = 0; q < 4; ++q) {
      __builtin_amdgcn_global_load_lds((gbl_t*)(gA0 + ((size_t)q * 32 * K + k0) * 2),
                                       (lds_t*)(lA0 + q * 4096), 16, 0, 0);
      __builtin_amdgcn_global_load_lds((gbl_t*)(gB0 + ((size_t)q * 32 * K + k0) * 2),
                                       (lds_t*)(lB0 + q * 4096), 16, 0, 0);
    }
    __syncthreads();

#pragma unroll
    for (int ks = 0; ks < 2; ++ks) {
      bf16x8 af[4], bfm[4];
#pragma unroll
      for (int mb = 0; mb < 4; ++mb)
        af[mb] = *reinterpret_cast<const bf16x8*>(
            (const uint8_t*)As + (wm * 64 + mb * 16 + c) * 128 + ((ks * 64 + g * 16) ^ kxor));
#pragma unroll
      for (int nb = 0; nb < 4; ++nb)
        bfm[nb] = *reinterpret_cast<const bf16x8*>(
            (const uint8_t*)Bs + (wn * 64 + nb * 16 + c) * 128 + ((ks * 64 + g * 16) ^ kxor));
      __builtin_amdgcn_s_setprio(1);
#pragma unroll
      for (int mb = 0; mb < 4; ++mb)
#pragma unroll
        for (int nb = 0; nb < 4; ++nb)
          acc[mb][nb] = __builtin_amdgcn_mfma_f32_16x16x32_bf16(af[mb], bfm[nb], acc[mb][nb], 0, 0, 0);
      __builtin_amdgcn_s_setprio(0);
    }
    __syncthreads();
  }

  const int rm0 = tm0 + wm * 64;
  const int cn0 = tn0 + wn * 64;
  const int sel = tn0 >> 10;
#pragma unroll
  for (int mb = 0; mb < 4; ++mb) {
#pragma unroll
    for (int nb = 0; nb < 4; ++nb) {
      f32x4 v2 = acc[mb][nb];
#pragma unroll
      for (int j = 0; j < 4; ++j) {
        int rm = rm0 + mb * 16 + g * 4 + j;
        int cn = cn0 + nb * 16 + c;
        float val = v2[j];
        if (MODE == 0) {
          int b = rm >> 11, s = rm & 2047;
          int dmn = cn & 1023;
          int h = dmn >> 6, d = dmn & 63;
          if (sel == 0) {
            Qb[(((size_t)(b * NH + h) * S_LEN + s) << 6) + d] = (__bf16)(val * 0.18033688f);
          } else if (sel == 1) {
            Kb[(((size_t)(b * NH + h) * S_LEN + s) << 6) + d] = (__bf16)val;
          } else {
            Vt[((size_t)(b * NH + h) * HD + d) * S_LEN + s] = (__bf16)val;
          }
        } else {
          Out[(size_t)rm * DM + cn] = val;
        }
      }
    }
  }
}

// ---------------- flash attention (causal, no-max exp2 softmax, KV-split) ----
// 1D grid, XCD-chunked work remap (T1). SPLIT=2 with liveness-culled partials.
template <int SPLIT>
__global__ __launch_bounds__(256, 3) void attn_kernel(
    const unsigned short* __restrict__ Qb, const unsigned short* __restrict__ Kb,
    const unsigned short* __restrict__ Vt, __bf16* __restrict__ Aout,
    __bf16* __restrict__ AP, float* __restrict__ Lp) {
  __shared__ __align__(16) unsigned short KVs[2][8192];   // 32KB
  __shared__ __align__(16) unsigned short Ps[4][32 * 72]; // per-wave P, 18KB

  const int t = threadIdx.x, lane = t & 63, w = t >> 6;
  const int g = lane >> 4, c = lane & 15;

  const int lin = (int)blockIdx.x;
  const int work = (lin & 7) * ((int)gridDim.x >> 3) + (lin >> 3);
  const int sp = work % SPLIT;
  const int qx = (NQ - 1) - ((work / SPLIT) & (NQ - 1));  // heavy q-tiles first
  const int bh = work / (SPLIT * NQ);
  const int b = bh >> 4, h = bh & 15;
  const int q0 = qx * 128 + w * 32;

  const unsigned short* Qp = Qb + (size_t)bh * S_LEN * HD;
  const uint8_t* Kg8 = (const uint8_t*)(Kb + (size_t)bh * S_LEN * HD);
  const uint8_t* Vg8 = (const uint8_t*)(Vt + (size_t)bh * HD * S_LEN);

  const int sr = t >> 3;
  const int scb = ((t & 7) << 4) ^ ((sr & 7) << 4);
  const uint8_t* Kst = Kg8 + (size_t)sr * 128 + scb;
  const uint8_t* Vst = Vg8 + (size_t)sr * (S_LEN * 2) + scb;
  uint8_t* Ls = (uint8_t*)&KVs[0][0];

#define STAGE(buf, kvb_) do {                                                  \
    uint8_t* kd = Ls + (buf) * 16384 + t * 16;                                 \
    const uint8_t* kg = Kst + (size_t)(kvb_) * 128;                            \
    const uint8_t* vg = Vst + (size_t)(kvb_) * 2;                              \
    __builtin_amdgcn_global_load_lds((gbl_t*)kg, (lds_t*)kd, 16, 0, 0);        \
    __builtin_amdgcn_global_load_lds((gbl_t*)(kg + 32 * 128),                  \
                                     (lds_t*)(kd + 4096), 16, 0, 0);           \
    __builtin_amdgcn_global_load_lds((gbl_t*)vg, (lds_t*)(kd + 8192), 16, 0, 0);\
    __builtin_amdgcn_global_load_lds((gbl_t*)(vg + (size_t)32 * S_LEN * 2),    \
                                     (lds_t*)(kd + 12288), 16, 0, 0);          \
  } while (0)

  bf16x8 qf[2][2];
#pragma unroll
  for (int mb = 0; mb < 2; ++mb)
#pragma unroll
    for (int ks = 0; ks < 2; ++ks)
      qf[mb][ks] = *reinterpret_cast<const bf16x8*>(
          Qp + (size_t)(q0 + mb * 16 + c) * HD + ks * 32 + g * 8);

  bf16x8 onesf;
#pragma unroll
  for (int i = 0; i < 8; ++i) onesf[i] = (__bf16)1.0f;

  f32x4 oacc[2][4] = {};
  f32x4 lacc[2] = {};

  const int kxor = (c & 7) << 4;
  const int n_total = 2 * qx + 2;
  const int chunk = (n_total + SPLIT - 1) / SPLIT;
  int t0 = sp * chunk; if (t0 > n_total) t0 = n_total;
  int t1 = t0 + chunk; if (t1 > n_total) t1 = n_total;
  const int nblk_w = (q0 >> 6) + 1;

  const int st0 = (t0 < n_total) ? t0 : (n_total - 1);
  STAGE(0, st0 * 64);
  __syncthreads();

  __bf16* psw = (__bf16*)&Ps[w][0];
  const int qr = q0 + c;

  for (int kb = t0; kb < t1; ++kb) {
    const int cur = (kb - t0) & 1;
    if (kb + 1 < t1) STAGE(cur ^ 1, (kb + 1) * 64);

    if (kb < nblk_w) {
      const int kvb = kb * 64;
      const uint8_t* KL = Ls + cur * 16384;
      const uint8_t* VL = KL + 8192;

      f32x4 sacc[2][4] = {};
      __builtin_amdgcn_s_setprio(1);
#pragma unroll
      for (int ks = 0; ks < 2; ++ks) {
#pragma unroll
        for (int nb = 0; nb < 4; ++nb) {
          bf16x8 kf = *reinterpret_cast<const bf16x8*>(
              KL + (nb * 16 + c) * 128 + ((ks * 64 + g * 16) ^ kxor));
          sacc[0][nb] = __builtin_amdgcn_mfma_f32_16x16x32_bf16(kf, qf[0][ks], sacc[0][nb], 0, 0, 0);
          sacc[1][nb] = __builtin_amdgcn_mfma_f32_16x16x32_bf16(kf, qf[1][ks], sacc[1][nb], 0, 0, 0);
        }
      }
      __builtin_amdgcn_s_setprio(0);

      bf16x8 vf0[4], vf1[4];
#pragma unroll
      for (int db = 0; db < 4; ++db) {
        vf0[db] = *reinterpret_cast<const bf16x8*>(
            VL + (db * 16 + c) * 128 + ((g * 16) ^ kxor));
        vf1[db] = *reinterpret_cast<const bf16x8*>(
            VL + (db * 16 + c) * 128 + ((64 + g * 16) ^ kxor));
      }

      if (kb == nblk_w - 1) {
#pragma unroll
        for (int mb = 0; mb < 2; ++mb) {
          const int qrm = qr + mb * 16;
#pragma unroll
          for (int nb = 0; nb < 4; ++nb) {
            const int key0 = kvb + nb * 16 + g * 4;
            float p0 = (key0 + 0 <= qrm) ? exp2_hw(sacc[mb][nb][0]) : 0.f;
            float p1 = (key0 + 1 <= qrm) ? exp2_hw(sacc[mb][nb][1]) : 0.f;
            float p2 = (key0 + 2 <= qrm) ? exp2_hw(sacc[mb][nb][2]) : 0.f;
            float p3 = (key0 + 3 <= qrm) ? exp2_hw(sacc[mb][nb][3]) : 0.f;
            u32x2 pk = {cvtpk_bf16(p0, p1), cvtpk_bf16(p2, p3)};
            *reinterpret_cast<u32x2*>(psw + (mb * 16 + c) * 72 + nb * 16 + g * 4) = pk;
          }
        }
      } else {
#pragma unroll
        for (int mb = 0; mb < 2; ++mb)
#pragma unroll
          for (int nb = 0; nb < 4; ++nb) {
            float p0 = exp2_hw(sacc[mb][nb][0]);
            float p1 = exp2_hw(sacc[mb][nb][1]);
            float p2 = exp2_hw(sacc[mb][nb][2]);
            float p3 = exp2_hw(sacc[mb][nb][3]);
            u32x2 pk = {cvtpk_bf16(p0, p1), cvtpk_bf16(p2, p3)};
            *reinterpret_cast<u32x2*>(psw + (mb * 16 + c) * 72 + nb * 16 + g * 4) = pk;
          }
      }

      bf16x8 pf0_0 = *reinterpret_cast<const bf16x8*>(psw + (c) * 72 + g * 8);
      bf16x8 pf0_1 = *reinterpret_cast<const bf16x8*>(psw + (c) * 72 + 32 + g * 8);
      bf16x8 pf1_0 = *reinterpret_cast<const bf16x8*>(psw + (16 + c) * 72 + g * 8);
      bf16x8 pf1_1 = *reinterpret_cast<const bf16x8*>(psw + (16 + c) * 72 + 32 + g * 8);

      __builtin_amdgcn_s_setprio(1);
      lacc[0] = __builtin_amdgcn_mfma_f32_16x16x32_bf16(pf0_0, onesf, lacc[0], 0, 0, 0);
      lacc[0] = __builtin_amdgcn_mfma_f32_16x16x32_bf16(pf0_1, onesf, lacc[0], 0, 0, 0);
      lacc[1] = __builtin_amdgcn_mfma_f32_16x16x32_bf16(pf1_0, onesf, lacc[1], 0, 0, 0);
      lacc[1] = __builtin_amdgcn_mfma_f32_16x16x32_bf16(pf1_1, onesf, lacc[1], 0, 0, 0);

#pragma unroll
      for (int db = 0; db < 4; ++db) {
        oacc[0][db] = __builtin_amdgcn_mfma_f32_16x16x32_bf16(pf0_0, vf0[db], oacc[0][db], 0, 0, 0);
        oacc[0][db] = __builtin_amdgcn_mfma_f32_16x16x32_bf16(pf0_1, vf1[db], oacc[0][db], 0, 0, 0);
        oacc[1][db] = __builtin_amdgcn_mfma_f32_16x16x32_bf16(pf1_0, vf0[db], oacc[1][db], 0, 0, 0);
        oacc[1][db] = __builtin_amdgcn_mfma_f32_16x16x32_bf16(pf1_1, vf1[db], oacc[1][db], 0, 0, 0);
      }
      __builtin_amdgcn_s_setprio(0);
    }
    __syncthreads();
  }
#undef STAGE

  if (SPLIT == 1) {
    float rl[2][4];
#pragma unroll
    for (int mb = 0; mb < 2; ++mb)
#pragma unroll
      for (int j = 0; j < 4; ++j) rl[mb][j] = 1.0f / lacc[mb][j];
#pragma unroll
    for (int mb = 0; mb < 2; ++mb)
#pragma unroll
      for (int db = 0; db < 4; ++db)
#pragma unroll
        for (int j = 0; j < 4; ++j) {
          float o = oacc[mb][db][j] * rl[mb][j];
          int s = q0 + mb * 16 + g * 4 + j;
          int d = db * 16 + c;
          Aout[(size_t)(b * S_LEN + s) * DM + h * HD + d] = (__bf16)o;
        }
  } else if (t0 < nblk_w) {
    __bf16* APs = AP + (size_t)(sp * (B_SZ * NH) + bh) * S_LEN * HD;
    float* Lps = Lp + (size_t)(sp * (B_SZ * NH) + bh) * S_LEN;
#pragma unroll
    for (int mb = 0; mb < 2; ++mb) {
#pragma unroll
      for (int db = 0; db < 4; ++db)
#pragma unroll
        for (int j = 0; j < 4; ++j) {
          int q = q0 + mb * 16 + g * 4 + j;
          APs[(size_t)q * HD + db * 16 + c] = (__bf16)oacc[mb][db][j];
        }
      if (c == 0) {
#pragma unroll
        for (int j = 0; j < 4; ++j)
          Lps[q0 + mb * 16 + g * 4 + j] = lacc[mb][j];
      }
    }
  }
}

// combine (SPLIT=2): Aout = (Σ live AP)/(Σ live L); liveness mirrors attn.
__global__ void attn_combine2(const __bf16* __restrict__ AP, const float* __restrict__ Lp,
                              __bf16* __restrict__ Aout) {
  const int NIT = B_SZ * NH * S_LEN * (HD / 8);
  int i = blockIdx.x * blockDim.x + threadIdx.x;
  int stride = gridDim.x * blockDim.x;
  const size_t SOFF = (size_t)(B_SZ * NH) * S_LEN * HD;
  const size_t LOFF = (size_t)(B_SZ * NH) * S_LEN;
  for (; i < NIT; i += stride) {
    int d8 = i & 7;
    int q = (i >> 3) & (S_LEN - 1);
    int bh = i >> 14;
    size_t base = ((size_t)bh * S_LEN + q) * HD + d8 * 8;
    size_t lbase = (size_t)bh * S_LEN + q;

    const int qx = q >> 7;
    const int chunk = qx + 1;
    const int nblk_w = (q >> 6) + 1;

    float acc8[8];
    {
      bf16x8 a0 = *reinterpret_cast<const bf16x8*>(AP + base);
#pragma unroll
      for (int k = 0; k < 8; ++k) acc8[k] = (float)a0[k];
    }
    float l = Lp[lbase];
    if (chunk < nblk_w) {
      bf16x8 a = *reinterpret_cast<const bf16x8*>(AP + SOFF + base);
#pragma unroll
      for (int k = 0; k < 8; ++k) acc8[k] += (float)a[k];
      l += Lp[LOFF + lbase];
    }
    float rl = 1.0f / l;
    int b = bh >> 4, h = bh & 15;
    bf16x8 o;
#pragma unroll
    for (int k = 0; k < 8; ++k) o[k] = (__bf16)(acc8[k] * rl);
    *reinterpret_cast<bf16x8*>(Aout + ((size_t)(b * S_LEN + q)) * DM + h * HD + d8 * 8) = o;
  }
}

// ---------------- launcher ----------------
extern "C" void kernel_launch(void* const* d_in, const int* in_sizes, int n_in,
                              void* d_out, int out_size, void* d_ws, size_t ws_size,
                              hipStream_t stream) {
  const float* x = (const float*)d_in[0];
  const float* wq = (const float*)d_in[1];
  const float* wk = (const float*)d_in[2];
  const float* wv = (const float*)d_in[3];
  const float* wo = (const float*)d_in[4];
  float* out = (float*)d_out;

  uint8_t* ws = (uint8_t*)d_ws;
  const size_t MB = 1024 * 1024;
  unsigned short* xb   = (unsigned short*)(ws);             // 16 MB (reused as Aout)
  unsigned short* wcat = (unsigned short*)(ws + 16 * MB);   // 6 MB; dead after qkv
  unsigned short* wob  = (unsigned short*)(ws + 22 * MB);   // 2 MB
  unsigned short* Qb   = (unsigned short*)(ws + 24 * MB);   // 16 MB
  unsigned short* Kb   = (unsigned short*)(ws + 40 * MB);   // 16 MB
  unsigned short* Vt   = (unsigned short*)(ws + 56 * MB);   // 16 MB
  __bf16* AP           = (__bf16*)(ws + 72 * MB);           // 32 MB (2 split partials)
  float* Lp            = (float*)(ws + 16 * MB);            // 1 MB overlay on dead wcat

  cvt_all<<<2048, 256, 0, stream>>>(x, wq, wk, wv, wo, (__bf16*)xb, (__bf16*)wcat);

  gemm64<0><<<dim3((3 * DM / 128) * (M_ROWS / 128)), 256, 0, stream>>>(
      xb, wcat, (__bf16*)Qb, (__bf16*)Kb, (__bf16*)Vt, nullptr, 3 * DM / 128);

  __bf16* Aout = (__bf16*)xb;  // x no longer needed
  if (ws_size >= (size_t)136 * MB) {
    attn_kernel<2><<<dim3(NQ * 2 * B_SZ * NH), 256, 0, stream>>>(
        Qb, Kb, Vt, Aout, AP, Lp);
    attn_combine2<<<2048, 256, 0, stream>>>(AP, Lp, Aout);
  } else {
    attn_kernel<1><<<dim3(NQ * B_SZ * NH), 256, 0, stream>>>(
        Qb, Kb, Vt, Aout, nullptr, nullptr);
  }

  gemm64<1><<<dim3((DM / 128) * (M_ROWS / 128)), 256, 0, stream>>>(
      xb, wob, nullptr, nullptr, nullptr, out, DM / 128);
}